// Round 1
// 159.925 us; speedup vs baseline: 1.0897x; 1.0897x over previous
//
#include <hip/hip_runtime.h>
#include <math.h>

#define B 8
#define S 128
#define D 256
#define H 8
#define T 129
#define HD 32
#define BT (B*T)
#define NEG_INF -1000000000.0f
#define LN_EPS 1e-5f

// ---------------------------------------------------------------------------
// Kernel 1: weight folds (tiny).
// ---------------------------------------------------------------------------
__global__ __launch_bounds__(256) void prep_w(
    const float* __restrict__ Wq, const float* __restrict__ bq,
    const float* __restrict__ Wk, const float* __restrict__ bk,
    const float* __restrict__ We2, const float* __restrict__ be2,
    const float* __restrict__ wa,
    float* __restrict__ Wqk, float* __restrict__ bqk,
    float* __restrict__ W2aT, float* __restrict__ econst)
{
    int id = blockIdx.x * 256 + threadIdx.x;
    if (id < 2048) {
        int c = id >> 3, h = id & 7;
        float s = 0.f;
        #pragma unroll
        for (int d = 0; d < HD; ++d) s = fmaf(Wq[c*D + h*HD + d], wa[d], s);
        Wqk[c*16 + h] = s;
    } else if (id < 4096) {
        int id2 = id - 2048; int c = id2 >> 3, h = id2 & 7;
        float s = 0.f;
        #pragma unroll
        for (int d = 0; d < HD; ++d) s = fmaf(Wk[c*D + h*HD + d], wa[HD + d], s);
        Wqk[c*16 + 8 + h] = s;
    } else if (id < 6144) {
        int id2 = id - 4096; int h = id2 / D, c = id2 % D;
        float s = 0.f;
        #pragma unroll
        for (int d = 0; d < HD; ++d) s = fmaf(We2[c*D + h*HD + d], wa[2*HD + d], s);
        W2aT[h*D + c] = s;
    } else if (id < 6152) {
        int h = id - 6144;
        float s = 0.f;
        #pragma unroll
        for (int d = 0; d < HD; ++d) s = fmaf(bq[h*HD + d], wa[d], s);
        bqk[h] = s;
    } else if (id < 6160) {
        int h = id - 6152;
        float s = 0.f;
        #pragma unroll
        for (int d = 0; d < HD; ++d) s = fmaf(bk[h*HD + d], wa[HD + d], s);
        bqk[8 + h] = s;
    } else if (id < 6168) {
        int h = id - 6160;
        float s = 0.f;
        #pragma unroll
        for (int d = 0; d < HD; ++d) s = fmaf(be2[h*HD + d], wa[2*HD + d], s);
        econst[h] = s;
    }
}

// ---------------------------------------------------------------------------
// Kernel 2: row-tiled GEMMs (v; U,V halves of edge GEMM) + row sums of U,V
//           + folded qdkd GEMM (blockIdx.y == 3), transposed output.
// ---------------------------------------------------------------------------
__global__ __launch_bounds__(256) void gemm3(
    const float* __restrict__ nv, const float* __restrict__ desc,
    const float* __restrict__ Wv, const float* __restrict__ bv,
    const float* __restrict__ We1, const float* __restrict__ be1,
    const float* __restrict__ Wqk, const float* __restrict__ bqk,
    float* __restrict__ v, float* __restrict__ U, float* __restrict__ V,
    float* __restrict__ sU, float* __restrict__ sV, float* __restrict__ qdkdT)
{
    const int which = blockIdx.y;
    const int tid = threadIdx.x;
    __shared__ float xs[16][D];
    __shared__ float psum[4][8];

    if (which == 3) {
        // qdkdT[c][t] = nv[t,:] @ Wqk[:,c] + bqk[c]
        if (blockIdx.x >= 65) return;
        const int r0 = blockIdx.x * 16;
        const int r = tid >> 4, c = tid & 15;
        for (int t = tid; t < 16 * D; t += 256) {
            int rr = r0 + (t >> 8);
            xs[t >> 8][t & 255] = (rr < BT) ? nv[rr * D + (t & 255)] : 0.f;
        }
        __syncthreads();
        float acc = 0.f;
        for (int kk = 0; kk < D; kk += 4) {
            float4 x = *(const float4*)&xs[r][kk];
            acc = fmaf(x.x, Wqk[(kk+0)*16 + c], acc);
            acc = fmaf(x.y, Wqk[(kk+1)*16 + c], acc);
            acc = fmaf(x.z, Wqk[(kk+2)*16 + c], acc);
            acc = fmaf(x.w, Wqk[(kk+3)*16 + c], acc);
        }
        const int rr = r0 + r;
        if (rr < BT) qdkdT[c*BT + rr] = acc + bqk[c];
        return;
    }

    const float* X; const float* W; const float* bias; float* out; int rows;
    if (which == 0)      { X = nv;   W = Wv;        bias = bv;  out = v; rows = BT; }
    else if (which == 1) { X = desc; W = We1;       bias = be1; out = U; rows = B*S; }
    else                 { X = desc; W = We1 + D*D; bias = nullptr; out = V; rows = B*S; }

    const int r0 = blockIdx.x * 8;
    if (r0 >= rows) return;

    #pragma unroll
    for (int r = 0; r < 8; ++r) {
        int rr = r0 + r;
        xs[r][tid] = (rr < rows) ? X[rr * D + tid] : 0.f;
    }
    __syncthreads();

    float acc[8] = {0.f,0.f,0.f,0.f,0.f,0.f,0.f,0.f};
    for (int kk = 0; kk < D; kk += 4) {
        float w0 = W[(kk+0)*D + tid];
        float w1 = W[(kk+1)*D + tid];
        float w2 = W[(kk+2)*D + tid];
        float w3 = W[(kk+3)*D + tid];
        #pragma unroll
        for (int r = 0; r < 8; ++r) {
            float4 x = *(const float4*)&xs[r][kk];
            acc[r] = fmaf(x.x, w0, acc[r]);
            acc[r] = fmaf(x.y, w1, acc[r]);
            acc[r] = fmaf(x.z, w2, acc[r]);
            acc[r] = fmaf(x.w, w3, acc[r]);
        }
    }
    const float bb = bias ? bias[tid] : 0.f;
    #pragma unroll
    for (int r = 0; r < 8; ++r) {
        int rr = r0 + r;
        if (rr < rows) out[rr * D + tid] = acc[r] + bb;
    }

    // Row sums for U / V (feeds separable LN mean in edge_attn).
    if (which >= 1) {
        const int wv = tid >> 6, ln = tid & 63;
        #pragma unroll
        for (int r = 0; r < 8; ++r) {
            float sps = acc[r] + bb;
            #pragma unroll
            for (int m = 32; m >= 1; m >>= 1) sps += __shfl_xor(sps, m);
            if (ln == 0) psum[wv][r] = sps;
        }
        __syncthreads();
        if (tid < 8) {
            float* dst = (which == 1) ? sU : sV;
            dst[r0 + tid] = psum[0][tid] + psum[1][tid] + psum[2][tid] + psum[3][tid];
        }
    }
}

// value-splitting butterfly over 8 head partials -> head `hmap(lane)` total
__device__ __forceinline__ float head_reduce(float* ph, int lane) {
    {
        const bool hi = (lane & 1);
        float k0 = hi ? ph[4] : ph[0], d0 = hi ? ph[0] : ph[4];
        float k1 = hi ? ph[5] : ph[1], d1 = hi ? ph[1] : ph[5];
        float k2 = hi ? ph[6] : ph[2], d2 = hi ? ph[2] : ph[6];
        float k3 = hi ? ph[7] : ph[3], d3 = hi ? ph[3] : ph[7];
        ph[0] = k0 + __shfl_xor(d0, 1);
        ph[1] = k1 + __shfl_xor(d1, 1);
        ph[2] = k2 + __shfl_xor(d2, 1);
        ph[3] = k3 + __shfl_xor(d3, 1);
    }
    {
        const bool hi = (lane & 2);
        float k0 = hi ? ph[2] : ph[0], d0 = hi ? ph[0] : ph[2];
        float k1 = hi ? ph[3] : ph[1], d1 = hi ? ph[1] : ph[3];
        ph[0] = k0 + __shfl_xor(d0, 2);
        ph[1] = k1 + __shfl_xor(d1, 2);
    }
    {
        const bool hi = (lane & 4);
        float k0 = hi ? ph[1] : ph[0], d0 = hi ? ph[0] : ph[1];
        ph[0] = k0 + __shfl_xor(d0, 4);
    }
    float r = ph[0];
    r += __shfl_xor(r, 8);
    r += __shfl_xor(r, 16);
    r += __shfl_xor(r, 32);
    return r;
}

// ---------------------------------------------------------------------------
// Kernel 3 (fused): edge LN+relu+head-dot -> softmax(+prior) -> ctx.
// mu is precomputed & separable (sU/sV); only the Sigma(y^2) reduce remains.
// 2-wide j interleave, no divergent skip (j==i computed, masked later).
// ---------------------------------------------------------------------------
__global__ __launch_bounds__(512, 4) void edge_attn(
    const float* __restrict__ U, const float* __restrict__ V,
    const float* __restrict__ W2aT, const float* __restrict__ econst,
    const float* __restrict__ ln_g, const float* __restrict__ ln_b,
    const float* __restrict__ qdkdT, const float* __restrict__ prior,
    const float* __restrict__ v, const float* __restrict__ ba,
    const float* __restrict__ sU, const float* __restrict__ sV,
    float* __restrict__ out_basis, float* __restrict__ out_attn)
{
    const int bid = blockIdx.x;      // b*T + i
    const int b = bid / T, i = bid % T;
    const int tid = threadIdx.x, lane = tid & 63, wid = tid >> 6;
    const int c0 = lane * 4;

    __shared__ float escl[H][132];
    __shared__ float pat[H][132];

    // ---- Phase A: edge scores ----
    const float4 g4 = *(const float4*)(ln_g + c0);
    const float4 b4 = *(const float4*)(ln_b + c0);
    float4 w[H];
    #pragma unroll
    for (int h = 0; h < H; ++h) w[h] = *(const float4*)(W2aT + h*D + c0);

    float4 u4i = make_float4(0.f, 0.f, 0.f, 0.f);
    float sUi = 0.f;
    if (i >= 1) {
        u4i = *(const float4*)(U + (size_t)(b*S + (i-1))*D + c0);
        sUi = sU[b*S + (i-1)];
    }

    const int hmap = 4*(lane&1) + 2*((lane>>1)&1) + ((lane>>2)&1);
    const float ecl = (lane < 8) ? econst[hmap] : 0.f;

    const int j0 = 1 + wid * 16;
    const float* Vb  = V  + (size_t)(b*S + (j0-1))*D + c0;
    const float* Ub  = U  + (size_t)(b*S + (j0-1))*D + c0;
    const float* sVb = sV + b*S + (j0-1);
    const float* sUb = sU + b*S + (j0-1);

    #pragma unroll 2
    for (int jj = 0; jj < 16; jj += 2) {
        const float4 va  = *(const float4*)(Vb + (size_t)jj*D);
        const float4 vb4 = *(const float4*)(Vb + (size_t)(jj+1)*D);
        float4 ua, ub; float su_a, su_b;
        if (i == 0) {
            ua = *(const float4*)(Ub + (size_t)jj*D);
            ub = *(const float4*)(Ub + (size_t)(jj+1)*D);
            su_a = sUb[jj]; su_b = sUb[jj+1];
        } else { ua = u4i; ub = u4i; su_a = sUi; su_b = sUi; }

        const float mua = (su_a + sVb[jj])   * (1.f/D);
        const float mub = (su_b + sVb[jj+1]) * (1.f/D);

        const float ya0 = ua.x + va.x,  ya1 = ua.y + va.y;
        const float ya2 = ua.z + va.z,  ya3 = ua.w + va.w;
        const float yb0 = ub.x + vb4.x, yb1 = ub.y + vb4.y;
        const float yb2 = ub.z + vb4.z, yb3 = ub.w + vb4.w;

        float s2a = fmaf(ya0, ya0, fmaf(ya1, ya1, fmaf(ya2, ya2, ya3 * ya3)));
        float s2b = fmaf(yb0, yb0, fmaf(yb1, yb1, fmaf(yb2, yb2, yb3 * yb3)));
        #pragma unroll
        for (int m = 32; m >= 1; m >>= 1) {
            s2a += __shfl_xor(s2a, m);
            s2b += __shfl_xor(s2b, m);
        }
        const float vara = fmaf(-mua, mua, s2a * (1.f/D));
        const float varb = fmaf(-mub, mub, s2b * (1.f/D));
        const float rsa = rsqrtf(vara + LN_EPS);
        const float rsb = rsqrtf(varb + LN_EPS);

        const float ta0 = fmaxf(fmaf((ya0 - mua) * rsa, g4.x, b4.x), 0.f);
        const float ta1 = fmaxf(fmaf((ya1 - mua) * rsa, g4.y, b4.y), 0.f);
        const float ta2 = fmaxf(fmaf((ya2 - mua) * rsa, g4.z, b4.z), 0.f);
        const float ta3 = fmaxf(fmaf((ya3 - mua) * rsa, g4.w, b4.w), 0.f);
        const float tb0 = fmaxf(fmaf((yb0 - mub) * rsb, g4.x, b4.x), 0.f);
        const float tb1 = fmaxf(fmaf((yb1 - mub) * rsb, g4.y, b4.y), 0.f);
        const float tb2 = fmaxf(fmaf((yb2 - mub) * rsb, g4.z, b4.z), 0.f);
        const float tb3 = fmaxf(fmaf((yb3 - mub) * rsb, g4.w, b4.w), 0.f);

        float pha[8], phb[8];
        #pragma unroll
        for (int h = 0; h < H; ++h) {
            pha[h] = fmaf(ta0, w[h].x, fmaf(ta1, w[h].y, fmaf(ta2, w[h].z, ta3 * w[h].w)));
            phb[h] = fmaf(tb0, w[h].x, fmaf(tb1, w[h].y, fmaf(tb2, w[h].z, tb3 * w[h].w)));
        }
        const float ra = head_reduce(pha, lane);
        const float rb = head_reduce(phb, lane);
        if (lane < 8) {
            escl[hmap][j0 + jj]     = ra + ecl;
            escl[hmap][j0 + jj + 1] = rb + ecl;
        }
    }
    __syncthreads();

    // ---- Phase B: softmax (wave = head) ----
    const int h = wid;
    const int bh = b*H + h;
    const float qdv = qdkdT[h*BT + b*T + i];
    const float ba0 = ba[0];
    const int j1 = 1 + lane, j2 = 65 + lane;
    const bool val1 = !(i >= 1 && j1 == i);
    const bool val2 = !(i >= 1 && j2 == i);
    const float* kT = qdkdT + (8 + h)*BT + b*T;

    float l1 = NEG_INF, l2 = NEG_INF;
    if (val1) {
        l1 = qdv + kT[j1] + escl[h][j1] + ba0;
        if (i >= 1) {
            float pr = prior[((size_t)bh*S + (i-1))*S + (j1-1)];
            pr = fminf(fmaxf(pr, 1e-6f), 1.f - 1e-6f);
            l1 += __logf(pr) - __logf(1.f - pr);
        }
    }
    if (val2) {
        l2 = qdv + kT[j2] + escl[h][j2] + ba0;
        if (i >= 1) {
            float pr = prior[((size_t)bh*S + (i-1))*S + (j2-1)];
            pr = fminf(fmaxf(pr, 1e-6f), 1.f - 1e-6f);
            l2 += __logf(pr) - __logf(1.f - pr);
        }
    }

    float m = fmaxf(l1, l2);
    #pragma unroll
    for (int mm = 32; mm >= 1; mm >>= 1) m = fmaxf(m, __shfl_xor(m, mm));
    const float e1 = val1 ? __expf(l1 - m) : 0.f;
    const float e2 = val2 ? __expf(l2 - m) : 0.f;
    float ssum = e1 + e2;
    #pragma unroll
    for (int mm = 32; mm >= 1; mm >>= 1) ssum += __shfl_xor(ssum, mm);
    const float inv = 1.f / ssum;
    const float a1 = e1 * inv, a2 = e2 * inv;

    float* arow = out_attn + (size_t)(bh*T + i)*T;
    arow[j1] = a1;
    arow[j2] = a2;
    if (lane == 0) arow[0] = 0.f;
    pat[h][j1] = a1;
    pat[h][j2] = a2;
    __syncthreads();

    // ---- Phase C: ctx (lane = (jg, dg); float4 loads of v) ----
    const int dg = lane & 7;      // d = dg*4 .. dg*4+3
    const int jg = lane >> 3;     // 8 groups x 16 j each
    const float* vbase = v + (size_t)(b*T)*D + h*HD + dg*4;
    float4 acc4 = make_float4(0.f, 0.f, 0.f, 0.f);
    #pragma unroll
    for (int k = 0; k < 16; ++k) {
        const int j = 1 + jg*16 + k;
        const float p = pat[h][j];
        const float4 vv = *(const float4*)(vbase + (size_t)j*D);
        acc4.x = fmaf(p, vv.x, acc4.x);
        acc4.y = fmaf(p, vv.y, acc4.y);
        acc4.z = fmaf(p, vv.z, acc4.z);
        acc4.w = fmaf(p, vv.w, acc4.w);
    }
    #pragma unroll
    for (int mm = 8; mm <= 32; mm <<= 1) {
        acc4.x += __shfl_xor(acc4.x, mm);
        acc4.y += __shfl_xor(acc4.y, mm);
        acc4.z += __shfl_xor(acc4.z, mm);
        acc4.w += __shfl_xor(acc4.w, mm);
    }
    if (jg == 0)
        *(float4*)(out_basis + ((size_t)(b*T + i)*H + h)*HD + dg*4) = acc4;
}

extern "C" void kernel_launch(void* const* d_in, const int* in_sizes, int n_in,
                              void* d_out, int out_size, void* d_ws, size_t ws_size,
                              hipStream_t stream) {
    const float* desc  = (const float*)d_in[0];
    const float* nv    = (const float*)d_in[1];
    const float* prior = (const float*)d_in[2];
    const float* Wq  = (const float*)d_in[3];
    const float* bq  = (const float*)d_in[4];
    const float* Wk  = (const float*)d_in[5];
    const float* bk  = (const float*)d_in[6];
    const float* Wv  = (const float*)d_in[7];
    const float* bv  = (const float*)d_in[8];
    const float* wa  = (const float*)d_in[9];
    const float* ba  = (const float*)d_in[10];
    const float* We1 = (const float*)d_in[11];
    const float* be1 = (const float*)d_in[12];
    const float* lng = (const float*)d_in[13];
    const float* lnb = (const float*)d_in[14];
    const float* We2 = (const float*)d_in[15];
    const float* be2 = (const float*)d_in[16];

    float* ws = (float*)d_ws;
    float* U     = ws; ws += B*S*D;
    float* V     = ws; ws += B*S*D;
    float* v     = ws; ws += B*T*D;
    float* Wqk   = ws; ws += D*16;
    float* bqk   = ws; ws += 16;
    float* W2aT  = ws; ws += H*D;
    float* ec    = ws; ws += H;
    float* qdkdT = ws; ws += 16*BT;
    float* sU    = ws; ws += B*S;
    float* sV    = ws; ws += B*S;

    float* out_basis = (float*)d_out;
    float* out_attn  = out_basis + B*T*H*HD;

    prep_w<<<dim3(25), 256, 0, stream>>>(Wq, bq, Wk, bk, We2, be2, wa,
                                         Wqk, bqk, W2aT, ec);
    gemm3<<<dim3(129, 4), 256, 0, stream>>>(nv, desc, Wv, bv, We1, be1,
                                            Wqk, bqk, v, U, V, sU, sV, qdkdT);
    edge_attn<<<dim3(B*T), 512, 0, stream>>>(U, V, W2aT, ec, lng, lnb,
                                             qdkdT, prior, v, ba, sU, sV,
                                             out_basis, out_attn);
}